// Round 15
// baseline (84.123 us; speedup 1.0000x reference)
//
#include <hip/hip_runtime.h>
#include <hip/hip_fp16.h>

// LGA2 fused: out = LGA(LGA(x,f),f), radius=2 (25 taps), fp32 in/out.
// x: [N=2, C=64, H=256, W=512], f: [N, 25, H, W], out like x.
//
// R15 = R13's PROVEN compute (fma_mix ROWM, frA/frB packed filters) plus
// ONLY the sync/prefetch restructure from R14 (isolating R14's failure):
//  - ONE lgkm barrier per channel (was 2): st double-buffered (st0/st1);
//    per-buffer audit: write->read separated by 1 barrier, read->rewrite
//    by 2 barriers.
//  - 2-deep prefetch: ch cc+2 issued at iter cc top, landed in iter cc+1
//    (~1.25 iters in flight >> ~900cy HBM latency). Loop unrolled x2 so
//    buffer parity is compile-time.
// Tile: temp 16x64, out 12x60, x region 20x68, USH=40 uints/row (f16 LDS).

typedef __fp16 h2v __attribute__((ext_vector_type(2)));

#define OH 12
#define OW 60
#define USH 40

__device__ __forceinline__ unsigned pkh(float a, float b) {
    union { h2v h; unsigned u; } c;
    c.h = __builtin_amdgcn_cvt_pkrtz(a, b);
    return c.u;
}

// acc += f16(fv half sf) * f16(xv half sx), f32 accumulate
#define M(ac, fv, xv, sf, sx) \
    asm("v_fma_mix_f32 %0, %1, %2, %0 op_sel:[" #sf "," #sx ",0] op_sel_hi:[1,1,0]" \
        : "+v"(ac) : "v"(fv), "v"(xv));

// One filter row (taps T..T+4) against window uints w0..w3 (rel halves 0..7):
// output col k accumulates f[tap]*x[half k+j]. (R13-proven.)
#define ROWM(T, w0, w1, w2, w3) \
  M(a0,frA[T+0],w0,0,0) M(a1,frA[T+0],w0,1,1) M(a2,frB[T+0],w1,0,0) M(a3,frB[T+0],w1,1,1) \
  M(a0,frA[T+1],w0,0,1) M(a1,frA[T+1],w1,1,0) M(a2,frB[T+1],w1,0,1) M(a3,frB[T+1],w2,1,0) \
  M(a0,frA[T+2],w1,0,0) M(a1,frA[T+2],w1,1,1) M(a2,frB[T+2],w2,0,0) M(a3,frB[T+2],w2,1,1) \
  M(a0,frA[T+3],w1,0,1) M(a1,frA[T+3],w2,1,0) M(a2,frB[T+3],w2,0,1) M(a3,frB[T+3],w3,1,0) \
  M(a0,frA[T+4],w2,0,0) M(a1,frA[T+4],w2,1,1) M(a2,frB[T+4],w3,0,0) M(a3,frB[T+4],w3,1,1)

#define PASS(BUF, ROWBASE) { \
    a0 = 0.f; a1 = 0.f; a2 = 0.f; a3 = 0.f; \
    _Pragma("unroll") \
    for (int i = 0; i < 5; ++i) { \
        const int b = ((ROWBASE) + i) * USH + 2 * s; \
        uint2 lo = *(const uint2*)&(BUF)[b]; \
        uint2 hi = *(const uint2*)&(BUF)[b + 2]; \
        ROWM(5 * i, lo.x, lo.y, hi.x, hi.y) \
    } }

// lgkm-only barrier: LDS ordered, global prefetch loads stay in flight
#define LBAR() { asm volatile("s_waitcnt lgkmcnt(0)" ::: "memory"); \
                 __builtin_amdgcn_s_barrier(); asm volatile("" ::: "memory"); }

// One channel CC: issue ch CC+2 -> NXI regs; p1 SXR->STB; land NXL(ch CC+1)
// -> SXL; barrier; p2 STB->out.
#define BODY(CC, SXR, SXL, STB, NXI0, NXI1, NXL0, NXL1) { \
    if ((CC) + 2 < CPB) { \
        if (ok0) NXI0 = *(const float4*)pfp0; \
        if (ok1) NXI1 = *(const float4*)pfp1; \
    } \
    pfp0 += HW; pfp1 += HW; \
    float a0, a1, a2, a3; \
    PASS(SXR, r) \
    (STB)[r * USH + 1 + 2 * s] = pkh(a0, a1); \
    (STB)[r * USH + 2 + 2 * s] = pkh(a2, a3); \
    if ((CC) + 1 < CPB) { \
        *(uint2*)&(SXL)[l0u] = make_uint2(pkh(NXL0.x, NXL0.y), pkh(NXL0.z, NXL0.w)); \
        if (has1) *(uint2*)&(SXL)[l1u] = make_uint2(pkh(NXL1.x, NXL1.y), pkh(NXL1.z, NXL1.w)); \
    } \
    LBAR(); \
    PASS(STB, rc - 2) \
    if (prow) { \
        if (s >= 1 && gwb + 1 < W)  *(float2*)op       = make_float2(a0, a1); \
        if (s <= 14 && gwb + 3 < W) *(float2*)(op + 2) = make_float2(a2, a3); \
    } \
    op += HW; \
}

__global__ __launch_bounds__(256)
void lga2_fused(const float* __restrict__ x, const float* __restrict__ f,
                float* __restrict__ out, int N, int C, int H, int W, int CPB) {
    const int tid = threadIdx.x;
    const int r = tid >> 4;            // temp-region row 0..15
    const int s = tid & 15;            // quad-strip 0..15
    const int oh0 = blockIdx.y * OH;
    const int ow0 = blockIdx.x * OW;
    const int CG = C / CPB;
    const int n  = blockIdx.z / CG;
    const int c0 = (blockIdx.z % CG) * CPB;
    const int HW = H * W;

    __shared__ unsigned sx0[20 * USH], sx1[20 * USH];  // x as f16, dbuf
    __shared__ unsigned st0[16 * USH], st1[16 * USH];  // temp as f16, dbuf

    // zero temp guard uints (uint 0 = halves 0,1; uint 33 = halves 66,67)
    if (tid < 64) {
        unsigned* stz = (tid < 32) ? st0 : st1;
        int i = tid & 31, row = i & 15;
        stz[row * USH + ((i & 16) ? 33 : 0)] = 0u;
    }

    // ---- filter registers: 25 taps x 2 packed half2 (R13 layout) ----
    const int gh_f = oh0 - 2 + r;
    const int gwb  = ow0 - 2 + 4 * s;
    const bool rowok = (gh_f >= 0) && (gh_f < H);
    const bool p0ok = rowok && (gwb >= 0) && (gwb + 1 < W);
    const bool p1ok = rowok && (gwb + 3 < W);
    const float* fb = f + (size_t)(n * 25) * HW + (size_t)(rowok ? gh_f : 0) * W;

    unsigned frA[25], frB[25];
    #pragma unroll
    for (int t = 0; t < 25; ++t) {
        float2 v01 = p0ok ? *(const float2*)(fb + (size_t)t * HW + gwb)
                          : make_float2(0.f, 0.f);
        float2 v23 = p1ok ? *(const float2*)(fb + (size_t)t * HW + gwb + 2)
                          : make_float2(0.f, 0.f);
        frA[t] = pkh(v01.x, v01.y);
        frB[t] = pkh(v23.x, v23.y);
        if ((t % 5) == 4) __builtin_amdgcn_sched_barrier(0);  // cap load burst
    }
    #pragma unroll
    for (int t = 0; t < 25; ++t)
        asm volatile("" : "+v"(frA[t]), "+v"(frB[t]));   // pin packed filters

    // ---- staging: 340 quads (20 rows x 17), linear uint2 per quad ----
    const int i1 = tid + 256;
    const bool has1 = (tid < 340 - 256);
    const int row0 = tid / 17, v0 = tid - row0 * 17;
    const int row1 = i1 / 17,  v1 = i1 - row1 * 17;
    const int g0h = oh0 - 4 + row0, g0c = ow0 - 4 + 4 * v0;
    const int g1h = oh0 - 4 + row1, g1c = ow0 - 4 + 4 * v1;
    const bool ok0 = (g0h >= 0) && (g0h < H) && (g0c >= 0) && (g0c + 3 < W);
    const bool ok1 = has1 && (g1h >= 0) && (g1h < H) && (g1c >= 0) && (g1c + 3 < W);
    const int off0 = ok0 ? (g0h * W + g0c) : 0;
    const int off1 = ok1 ? (g1h * W + g1c) : 0;
    const int l0u = row0 * USH + 2 * v0;
    const int l1u = row1 * USH + 2 * v1;

    const float4 z4 = make_float4(0.f, 0.f, 0.f, 0.f);
    const float* xc = x + (size_t)(n * C + c0) * HW;

    // prologue: stage ch0 -> sx0; issue ch1 -> nxB regs; pointers at ch2
    {
        float4 p = ok0 ? *(const float4*)(xc + off0) : z4;
        *(uint2*)&sx0[l0u] = make_uint2(pkh(p.x, p.y), pkh(p.z, p.w));
        if (has1) {
            float4 q = ok1 ? *(const float4*)(xc + off1) : z4;
            *(uint2*)&sx0[l1u] = make_uint2(pkh(q.x, q.y), pkh(q.z, q.w));
        }
    }
    float4 nxA0 = z4, nxA1 = z4, nxB0 = z4, nxB1 = z4;
    if (CPB > 1) {
        if (ok0) nxB0 = *(const float4*)(xc + HW + off0);
        if (ok1) nxB1 = *(const float4*)(xc + HW + off1);
    }
    const float* pfp0 = xc + 2 * (size_t)HW + off0;
    const float* pfp1 = xc + 2 * (size_t)HW + off1;
    __syncthreads();

    const bool prow = (r >= 2) && (r <= 13) && (gh_f < H);
    const int rc = (r < 2) ? 2 : ((r > 13) ? 13 : r);
    float* op = out + ((size_t)(n * C + c0) * H + gh_f) * W + gwb;

    for (int cc = 0; cc < CPB; cc += 2) {
        BODY(cc,     sx0, sx1, st0, nxA0, nxA1, nxB0, nxB1)   // even channel
        BODY(cc + 1, sx1, sx0, st1, nxB0, nxB1, nxA0, nxA1)   // odd channel
    }
}

extern "C" void kernel_launch(void* const* d_in, const int* in_sizes, int n_in,
                              void* d_out, int out_size, void* d_ws, size_t ws_size,
                              hipStream_t stream) {
    const float* x = (const float*)d_in[0];
    const float* f = (const float*)d_in[1];
    float* out = (float*)d_out;

    const int N = 2, C = 64, H = 256, W = 512;
    const int CPB = 16;                        // 4 channel groups
    const int CG = C / CPB;

    dim3 grid((W + OW - 1) / OW,               // 9
              (H + OH - 1) / OH,               // 22
              N * CG);                         // 8  -> 1584 blocks of 256 thr
    lga2_fused<<<grid, 256, 0, stream>>>(x, f, out, N, C, H, W, CPB);
}

// Round 17
// 75.633 us; speedup vs baseline: 1.1123x; 1.1123x over previous
//
#include <hip/hip_runtime.h>
#include <hip/hip_fp16.h>

// LGA2 fused: out = LGA(LGA(x,f),f), radius=2 (25 taps), fp32 in/out.
// x: [N=2, C=64, H=256, W=512], f: [N, 25, H, W], out like x.
//
// R16 = R13 (79us, passed) with ONE change: v_pk_fma_f16 packed math.
//  - Per filter row: 10 pk_fma (2 FMAs each) + 3 alignbit x-repacks, vs
//    R13's 20 half-rate fma_mix. Filter packing frA/frB unchanged (proven):
//    frA[t]=(f_t@col0,f_t@col1) matches x-pair (x_j, x_{j+1}).
//  - Packed-f16 accumulation in TWO chains (even/odd rows, <=15 products)
//    merged by v_pk_add_f16; p1 result stored to f16 temp DIRECTLY (no
//    cvt_pkrtz); p2 unpacks to f32 for the global store.
//  - Everything else verbatim R13: 2 lgkm barriers/channel, 1-deep
//    prefetch landed at iter end, CPB=16, USH=40, tile temp 16x64/out 12x60.

typedef __fp16 h2v __attribute__((ext_vector_type(2)));

#define OH 12
#define OW 60
#define USH 40

__device__ __forceinline__ unsigned pkh(float a, float b) {
    union { h2v h; unsigned u; } c;
    c.h = __builtin_amdgcn_cvt_pkrtz(a, b);
    return c.u;
}

// packed: ac.h[i] += fv.h[i] * xv.h[i]
#define PKF(ac, fv, xv) \
    asm("v_pk_fma_f16 %0, %1, %2, %0" : "+v"(ac) : "v"(fv), "v"(xv));

// filter row i (taps 5i..5i+4) vs window uints w0..w3 (rel halves 0..7).
// col-pair(0,1) accumulates into E01/O01 (even/odd row chains), (2,3) into
// E23/O23. x-pairs: col01 j=0..4 -> w0,A01,w1,A12,w2 ; col23 -> w1,A12,w2,A23,w3.
#define ROWP(i, w0, w1, w2, w3, D01, D23) { \
    const unsigned A01 = ((w0) >> 16) | ((w1) << 16); \
    const unsigned A12 = ((w1) >> 16) | ((w2) << 16); \
    const unsigned A23 = ((w2) >> 16) | ((w3) << 16); \
    PKF(D01, frA[5*(i)+0], w0)  PKF(D01, frA[5*(i)+1], A01) \
    PKF(D01, frA[5*(i)+2], w1)  PKF(D01, frA[5*(i)+3], A12) \
    PKF(D01, frA[5*(i)+4], w2) \
    PKF(D23, frB[5*(i)+0], w1)  PKF(D23, frB[5*(i)+1], A12) \
    PKF(D23, frB[5*(i)+2], w2)  PKF(D23, frB[5*(i)+3], A23) \
    PKF(D23, frB[5*(i)+4], w3) }

// One pass over 5 rows starting at ROWBASE in BUF; results s01,s23 packed f16.
#define PASSP(BUF, ROWBASE) { \
    unsigned e01 = 0u, o01 = 0u, e23 = 0u, o23 = 0u; \
    _Pragma("unroll") \
    for (int i = 0; i < 5; ++i) { \
        const int b = ((ROWBASE) + i) * USH + 2 * s; \
        uint2 lo = *(const uint2*)&(BUF)[b]; \
        uint2 hi = *(const uint2*)&(BUF)[b + 2]; \
        if (i & 1) { ROWP(i, lo.x, lo.y, hi.x, hi.y, o01, o23) } \
        else       { ROWP(i, lo.x, lo.y, hi.x, hi.y, e01, e23) } \
    } \
    asm("v_pk_add_f16 %0, %1, %2" : "=v"(s01) : "v"(e01), "v"(o01)); \
    asm("v_pk_add_f16 %0, %1, %2" : "=v"(s23) : "v"(e23), "v"(o23)); }

// lgkm-only barrier: LDS ordered, global prefetch loads stay in flight
#define LBAR() { asm volatile("s_waitcnt lgkmcnt(0)" ::: "memory"); \
                 __builtin_amdgcn_s_barrier(); asm volatile("" ::: "memory"); }

__global__ __launch_bounds__(256)
void lga2_fused(const float* __restrict__ x, const float* __restrict__ f,
                float* __restrict__ out, int N, int C, int H, int W, int CPB) {
    const int tid = threadIdx.x;
    const int r = tid >> 4;            // temp-region row 0..15
    const int s = tid & 15;            // quad-strip 0..15 (temp cols 4s..4s+3)
    const int oh0 = blockIdx.y * OH;
    const int ow0 = blockIdx.x * OW;
    const int CG = C / CPB;
    const int n  = blockIdx.z / CG;
    const int c0 = (blockIdx.z % CG) * CPB;
    const int HW = H * W;

    __shared__ unsigned sxU[2][20 * USH];   // x as f16: 20 rows x 80 halves
    __shared__ unsigned stU[16 * USH];      // temp as f16: [2g][64][2g] halves

    // zero temp guard uints (uint 0 = halves 0,1; uint 33 = halves 66,67)
    if (tid < 32) {
        int row = tid & 15;
        stU[row * USH + ((tid & 16) ? 33 : 0)] = 0u;
    }

    // ---- filter registers: 25 taps x 2 packed half2 (R13 layout) ----
    const int gh_f = oh0 - 2 + r;          // this thread's temp/out row
    const int gwb  = ow0 - 2 + 4 * s;      // first col of the quad
    const bool rowok = (gh_f >= 0) && (gh_f < H);
    const bool p0ok = rowok && (gwb >= 0) && (gwb + 1 < W);
    const bool p1ok = rowok && (gwb + 3 < W);
    const float* fb = f + (size_t)(n * 25) * HW + (size_t)(rowok ? gh_f : 0) * W;

    unsigned frA[25], frB[25];
    #pragma unroll
    for (int t = 0; t < 25; ++t) {
        float2 v01 = p0ok ? *(const float2*)(fb + (size_t)t * HW + gwb)
                          : make_float2(0.f, 0.f);
        float2 v23 = p1ok ? *(const float2*)(fb + (size_t)t * HW + gwb + 2)
                          : make_float2(0.f, 0.f);
        frA[t] = pkh(v01.x, v01.y);
        frB[t] = pkh(v23.x, v23.y);
        if ((t % 5) == 4) __builtin_amdgcn_sched_barrier(0);  // cap load burst
    }
    #pragma unroll
    for (int t = 0; t < 25; ++t)
        asm volatile("" : "+v"(frA[t]), "+v"(frB[t]));   // pin packed filters

    // ---- staging: 340 quads (20 rows x 17), linear uint2 per quad ----
    const int i1 = tid + 256;
    const bool has1 = (tid < 340 - 256);
    const int row0 = tid / 17, v0 = tid - row0 * 17;
    const int row1 = i1 / 17,  v1 = i1 - row1 * 17;
    const int g0h = oh0 - 4 + row0, g0c = ow0 - 4 + 4 * v0;
    const int g1h = oh0 - 4 + row1, g1c = ow0 - 4 + 4 * v1;
    const bool ok0 = (g0h >= 0) && (g0h < H) && (g0c >= 0) && (g0c + 3 < W);
    const bool ok1 = has1 && (g1h >= 0) && (g1h < H) && (g1c >= 0) && (g1c + 3 < W);
    const int off0 = ok0 ? (g0h * W + g0c) : 0;
    const int off1 = ok1 ? (g1h * W + g1c) : 0;
    const int l0u = row0 * USH + 2 * v0;
    const int l1u = row1 * USH + 2 * v1;

    const float4 z4 = make_float4(0.f, 0.f, 0.f, 0.f);
    const float* xc = x + (size_t)(n * C + c0) * HW;

    {   // prologue: stage channel 0 into buffer 0 (zeros for OOB quads)
        float4 p = ok0 ? *(const float4*)(xc + off0) : z4;
        *(uint2*)&sxU[0][l0u] = make_uint2(pkh(p.x, p.y), pkh(p.z, p.w));
        if (has1) {
            float4 q = ok1 ? *(const float4*)(xc + off1) : z4;
            *(uint2*)&sxU[0][l1u] = make_uint2(pkh(q.x, q.y), pkh(q.z, q.w));
        }
    }
    __syncthreads();

    const bool prow = (r >= 2) && (r <= 13) && (gh_f < H);
    const int rc = (r < 2) ? 2 : ((r > 13) ? 13 : r);   // clamp for p2 reads
    float* op = out + ((size_t)(n * C + c0) * H + gh_f) * W + gwb;

    int cur = 0;
    for (int cc = 0; cc < CPB; ++cc) {
        // issue prefetch for channel cc+1 (landed at iteration end)
        float4 nx0 = z4, nx1 = z4;
        const bool pf = (cc + 1 < CPB);
        if (pf) {
            const float* xn = xc + (size_t)(cc + 1) * HW;
            if (ok0) nx0 = *(const float4*)(xn + off0);
            if (ok1) nx1 = *(const float4*)(xn + off1);
        }

        // ---- pass 1: temp(r, 4s..4s+3) in packed f16 ----
        unsigned s01, s23;
        PASSP(sxU[cur], r)
        stU[r * USH + 1 + 2 * s] = s01;   // storage halves 2+4s..: (a0,a1)
        stU[r * USH + 2 + 2 * s] = s23;   // (a2,a3)
        LBAR();   // temp visible

        // ---- pass 2: same pattern on temp; unpack to f32 for store ----
        PASSP(stU, rc - 2)
        if (prow) {
            union { unsigned u; h2v h; } U01, U23;
            U01.u = s01; U23.u = s23;
            if (s >= 1 && gwb + 1 < W)
                *(float2*)op = make_float2((float)U01.h.x, (float)U01.h.y);
            if (s <= 14 && gwb + 3 < W)
                *(float2*)(op + 2) = make_float2((float)U23.h.x, (float)U23.h.y);
        }

        // ---- land prefetch into the other buffer ----
        if (pf) {
            *(uint2*)&sxU[cur ^ 1][l0u] = make_uint2(pkh(nx0.x, nx0.y), pkh(nx0.z, nx0.w));
            if (has1)
                *(uint2*)&sxU[cur ^ 1][l1u] = make_uint2(pkh(nx1.x, nx1.y), pkh(nx1.z, nx1.w));
        }
        LBAR();   // next x visible; temp reads drained before next p1 write
        cur ^= 1;
        op += HW;
    }
}

extern "C" void kernel_launch(void* const* d_in, const int* in_sizes, int n_in,
                              void* d_out, int out_size, void* d_ws, size_t ws_size,
                              hipStream_t stream) {
    const float* x = (const float*)d_in[0];
    const float* f = (const float*)d_in[1];
    float* out = (float*)d_out;

    const int N = 2, C = 64, H = 256, W = 512;
    const int CPB = 16;                        // 4 channel groups
    const int CG = C / CPB;

    dim3 grid((W + OW - 1) / OW,               // 9
              (H + OH - 1) / OH,               // 22
              N * CG);                         // 8  -> 1584 blocks of 256 thr
    lga2_fused<<<grid, 256, 0, stream>>>(x, f, out, N, C, H, W, CPB);
}

// Round 18
// 74.271 us; speedup vs baseline: 1.1326x; 1.0183x over previous
//
#include <hip/hip_runtime.h>
#include <hip/hip_fp16.h>

// LGA2 fused: out = LGA(LGA(x,f),f), radius=2 (25 taps), fp32 in/out.
// x: [N=2, C=64, H=256, W=512], f: [N, 25, H, W], out like x.
//
// R18 = R17 (75.6us, passed) + filter-cost amortization:
//  - CPB=32 (was 16): each filter-register load serves 32 channels ->
//    filter HBM traffic halves (FETCH ~167 -> ~117MB), startup amortized 2x.
//  - Filter loads in 2 batches (sched_barrier after t=12 only, was every 5):
//    startup latency ~2x900cy instead of 5x900cy per block.
// Compute/sync verbatim R17: v_pk_fma_f16 packed math, two f16 accumulation
// chains (even/odd rows) merged by pk_add, f16 LDS for x and temp, 2
// lgkm-only barriers/channel, 1-deep prefetch landed at iteration end.
// Tile: temp 16x64, out 12x60, x region 20x68, USH=40 uints/row.

typedef __fp16 h2v __attribute__((ext_vector_type(2)));

#define OH 12
#define OW 60
#define USH 40

__device__ __forceinline__ unsigned pkh(float a, float b) {
    union { h2v h; unsigned u; } c;
    c.h = __builtin_amdgcn_cvt_pkrtz(a, b);
    return c.u;
}

// packed: ac.h[i] += fv.h[i] * xv.h[i]
#define PKF(ac, fv, xv) \
    asm("v_pk_fma_f16 %0, %1, %2, %0" : "+v"(ac) : "v"(fv), "v"(xv));

// filter row i (taps 5i..5i+4) vs window uints w0..w3 (rel halves 0..7).
// col-pair(0,1) accumulates into D01 chain, (2,3) into D23.
// x-pairs: col01 j=0..4 -> w0,A01,w1,A12,w2 ; col23 -> w1,A12,w2,A23,w3.
#define ROWP(i, w0, w1, w2, w3, D01, D23) { \
    const unsigned A01 = ((w0) >> 16) | ((w1) << 16); \
    const unsigned A12 = ((w1) >> 16) | ((w2) << 16); \
    const unsigned A23 = ((w2) >> 16) | ((w3) << 16); \
    PKF(D01, frA[5*(i)+0], w0)  PKF(D01, frA[5*(i)+1], A01) \
    PKF(D01, frA[5*(i)+2], w1)  PKF(D01, frA[5*(i)+3], A12) \
    PKF(D01, frA[5*(i)+4], w2) \
    PKF(D23, frB[5*(i)+0], w1)  PKF(D23, frB[5*(i)+1], A12) \
    PKF(D23, frB[5*(i)+2], w2)  PKF(D23, frB[5*(i)+3], A23) \
    PKF(D23, frB[5*(i)+4], w3) }

// One pass over 5 rows starting at ROWBASE in BUF; results s01,s23 packed f16.
#define PASSP(BUF, ROWBASE) { \
    unsigned e01 = 0u, o01 = 0u, e23 = 0u, o23 = 0u; \
    _Pragma("unroll") \
    for (int i = 0; i < 5; ++i) { \
        const int b = ((ROWBASE) + i) * USH + 2 * s; \
        uint2 lo = *(const uint2*)&(BUF)[b]; \
        uint2 hi = *(const uint2*)&(BUF)[b + 2]; \
        if (i & 1) { ROWP(i, lo.x, lo.y, hi.x, hi.y, o01, o23) } \
        else       { ROWP(i, lo.x, lo.y, hi.x, hi.y, e01, e23) } \
    } \
    asm("v_pk_add_f16 %0, %1, %2" : "=v"(s01) : "v"(e01), "v"(o01)); \
    asm("v_pk_add_f16 %0, %1, %2" : "=v"(s23) : "v"(e23), "v"(o23)); }

// lgkm-only barrier: LDS ordered, global prefetch loads stay in flight
#define LBAR() { asm volatile("s_waitcnt lgkmcnt(0)" ::: "memory"); \
                 __builtin_amdgcn_s_barrier(); asm volatile("" ::: "memory"); }

__global__ __launch_bounds__(256)
void lga2_fused(const float* __restrict__ x, const float* __restrict__ f,
                float* __restrict__ out, int N, int C, int H, int W, int CPB) {
    const int tid = threadIdx.x;
    const int r = tid >> 4;            // temp-region row 0..15
    const int s = tid & 15;            // quad-strip 0..15 (temp cols 4s..4s+3)
    const int oh0 = blockIdx.y * OH;
    const int ow0 = blockIdx.x * OW;
    const int CG = C / CPB;
    const int n  = blockIdx.z / CG;
    const int c0 = (blockIdx.z % CG) * CPB;
    const int HW = H * W;

    __shared__ unsigned sxU[2][20 * USH];   // x as f16: 20 rows x 80 halves
    __shared__ unsigned stU[16 * USH];      // temp as f16: [2g][64][2g] halves

    // zero temp guard uints (uint 0 = halves 0,1; uint 33 = halves 66,67)
    if (tid < 32) {
        int row = tid & 15;
        stU[row * USH + ((tid & 16) ? 33 : 0)] = 0u;
    }

    // ---- filter registers: 25 taps x 2 packed half2 (R13 layout) ----
    const int gh_f = oh0 - 2 + r;          // this thread's temp/out row
    const int gwb  = ow0 - 2 + 4 * s;      // first col of the quad
    const bool rowok = (gh_f >= 0) && (gh_f < H);
    const bool p0ok = rowok && (gwb >= 0) && (gwb + 1 < W);
    const bool p1ok = rowok && (gwb + 3 < W);
    const float* fb = f + (size_t)(n * 25) * HW + (size_t)(rowok ? gh_f : 0) * W;

    unsigned frA[25], frB[25];
    #pragma unroll
    for (int t = 0; t < 25; ++t) {
        float2 v01 = p0ok ? *(const float2*)(fb + (size_t)t * HW + gwb)
                          : make_float2(0.f, 0.f);
        float2 v23 = p1ok ? *(const float2*)(fb + (size_t)t * HW + gwb + 2)
                          : make_float2(0.f, 0.f);
        frA[t] = pkh(v01.x, v01.y);
        frB[t] = pkh(v23.x, v23.y);
        if (t == 12) __builtin_amdgcn_sched_barrier(0);  // 2 load batches
    }
    #pragma unroll
    for (int t = 0; t < 25; ++t)
        asm volatile("" : "+v"(frA[t]), "+v"(frB[t]));   // pin packed filters

    // ---- staging: 340 quads (20 rows x 17), linear uint2 per quad ----
    const int i1 = tid + 256;
    const bool has1 = (tid < 340 - 256);
    const int row0 = tid / 17, v0 = tid - row0 * 17;
    const int row1 = i1 / 17,  v1 = i1 - row1 * 17;
    const int g0h = oh0 - 4 + row0, g0c = ow0 - 4 + 4 * v0;
    const int g1h = oh0 - 4 + row1, g1c = ow0 - 4 + 4 * v1;
    const bool ok0 = (g0h >= 0) && (g0h < H) && (g0c >= 0) && (g0c + 3 < W);
    const bool ok1 = has1 && (g1h >= 0) && (g1h < H) && (g1c >= 0) && (g1c + 3 < W);
    const int off0 = ok0 ? (g0h * W + g0c) : 0;
    const int off1 = ok1 ? (g1h * W + g1c) : 0;
    const int l0u = row0 * USH + 2 * v0;
    const int l1u = row1 * USH + 2 * v1;

    const float4 z4 = make_float4(0.f, 0.f, 0.f, 0.f);
    const float* xc = x + (size_t)(n * C + c0) * HW;

    {   // prologue: stage channel 0 into buffer 0 (zeros for OOB quads)
        float4 p = ok0 ? *(const float4*)(xc + off0) : z4;
        *(uint2*)&sxU[0][l0u] = make_uint2(pkh(p.x, p.y), pkh(p.z, p.w));
        if (has1) {
            float4 q = ok1 ? *(const float4*)(xc + off1) : z4;
            *(uint2*)&sxU[0][l1u] = make_uint2(pkh(q.x, q.y), pkh(q.z, q.w));
        }
    }
    __syncthreads();

    const bool prow = (r >= 2) && (r <= 13) && (gh_f < H);
    const int rc = (r < 2) ? 2 : ((r > 13) ? 13 : r);   // clamp for p2 reads
    float* op = out + ((size_t)(n * C + c0) * H + gh_f) * W + gwb;

    int cur = 0;
    for (int cc = 0; cc < CPB; ++cc) {
        // issue prefetch for channel cc+1 (landed at iteration end)
        float4 nx0 = z4, nx1 = z4;
        const bool pf = (cc + 1 < CPB);
        if (pf) {
            const float* xn = xc + (size_t)(cc + 1) * HW;
            if (ok0) nx0 = *(const float4*)(xn + off0);
            if (ok1) nx1 = *(const float4*)(xn + off1);
        }

        // ---- pass 1: temp(r, 4s..4s+3) in packed f16 ----
        unsigned s01, s23;
        PASSP(sxU[cur], r)
        stU[r * USH + 1 + 2 * s] = s01;   // storage halves 2+4s..: (a0,a1)
        stU[r * USH + 2 + 2 * s] = s23;   // (a2,a3)
        LBAR();   // temp visible

        // ---- pass 2: same pattern on temp; unpack to f32 for store ----
        PASSP(stU, rc - 2)
        if (prow) {
            union { unsigned u; h2v h; } U01, U23;
            U01.u = s01; U23.u = s23;
            if (s >= 1 && gwb + 1 < W)
                *(float2*)op = make_float2((float)U01.h.x, (float)U01.h.y);
            if (s <= 14 && gwb + 3 < W)
                *(float2*)(op + 2) = make_float2((float)U23.h.x, (float)U23.h.y);
        }

        // ---- land prefetch into the other buffer ----
        if (pf) {
            *(uint2*)&sxU[cur ^ 1][l0u] = make_uint2(pkh(nx0.x, nx0.y), pkh(nx0.z, nx0.w));
            if (has1)
                *(uint2*)&sxU[cur ^ 1][l1u] = make_uint2(pkh(nx1.x, nx1.y), pkh(nx1.z, nx1.w));
        }
        LBAR();   // next x visible; temp reads drained before next p1 write
        cur ^= 1;
        op += HW;
    }
}

extern "C" void kernel_launch(void* const* d_in, const int* in_sizes, int n_in,
                              void* d_out, int out_size, void* d_ws, size_t ws_size,
                              hipStream_t stream) {
    const float* x = (const float*)d_in[0];
    const float* f = (const float*)d_in[1];
    float* out = (float*)d_out;

    const int N = 2, C = 64, H = 256, W = 512;
    const int CPB = 32;                        // 2 channel groups
    const int CG = C / CPB;

    dim3 grid((W + OW - 1) / OW,               // 9
              (H + OH - 1) / OH,               // 22
              N * CG);                         // 4  -> 792 blocks of 256 thr
    lga2_fused<<<grid, 256, 0, stream>>>(x, f, out, N, C, H, W, CPB);
}